// Round 1
// 337.214 us; speedup vs baseline: 1.0014x; 1.0014x over previous
//
#include <hip/hip_runtime.h>
#include <stdint.h>

// Problem constants (B=8, M=4096, N=K=1024, D=1024)
#define RROWS 32768   // B*M
#define KDIM  1024    // N
#define DDIM  1024

typedef __bf16 bf16;
typedef __bf16 bf16x4 __attribute__((ext_vector_type(4)));
typedef __bf16 bf16x8 __attribute__((ext_vector_type(8)));
typedef float  f32x4  __attribute__((ext_vector_type(4)));

typedef __attribute__((address_space(1))) const unsigned int* gas_ptr;
typedef __attribute__((address_space(3))) unsigned int* las_ptr;

// ---------------------------------------------------------------------------
// Prep 1: Gt[d][k] = gamma[k] * w[k][d]  (bf16, transposed). 64x64 LDS tiles.
// ---------------------------------------------------------------------------
__global__ __launch_bounds__(256) void prep_gt(const float* __restrict__ w,
                                               const float* __restrict__ gamma,
                                               bf16* __restrict__ Gt) {
    __shared__ float tile[64][65];
    const int k0 = blockIdx.x * 64;
    const int d0 = blockIdx.y * 64;
    const int t  = threadIdx.x;
    const int col4 = (t & 15) * 4;
    const int rowb = t >> 4;
#pragma unroll
    for (int r = 0; r < 4; ++r) {
        const int k = rowb + r * 16;
        const float4 v = *(const float4*)&w[(size_t)(k0 + k) * DDIM + d0 + col4];
        const float g = gamma[k0 + k];
        tile[k][col4 + 0] = v.x * g;
        tile[k][col4 + 1] = v.y * g;
        tile[k][col4 + 2] = v.z * g;
        tile[k][col4 + 3] = v.w * g;
    }
    __syncthreads();
#pragma unroll
    for (int r = 0; r < 2; ++r) {
        const int d  = (t >> 3) + r * 32;
        const int ks = (t & 7) * 8;
        bf16x8 o;
#pragma unroll
        for (int j = 0; j < 8; ++j) o[j] = (bf16)tile[ks + j][d];
        *(bf16x8*)&Gt[(size_t)(d0 + d) * KDIM + k0 + ks] = o;
    }
}

// ---------------------------------------------------------------------------
// Prep 2a/2b: gw[d] = sum_k gamma*w (fallback path only), cvec[d] = sum_k beta*w + b
// ---------------------------------------------------------------------------
__global__ __launch_bounds__(256) void prep_part(const float* __restrict__ w,
                                                 const float* __restrict__ gamma,
                                                 const float* __restrict__ beta,
                                                 float* __restrict__ partG,
                                                 float* __restrict__ partB) {
    const int d  = blockIdx.x * 256 + threadIdx.x;
    const int kc = blockIdx.y;
    float ag = 0.f, ab = 0.f;
    for (int k = kc * 64; k < kc * 64 + 64; ++k) {
        const float wv = w[(size_t)k * DDIM + d];
        ag += gamma[k] * wv;
        ab += beta[k] * wv;
    }
    partG[(size_t)kc * DDIM + d] = ag;
    partB[(size_t)kc * DDIM + d] = ab;
}

__global__ __launch_bounds__(256) void prep_reduce(const float* __restrict__ partG,
                                                   const float* __restrict__ partB,
                                                   const float* __restrict__ b,
                                                   float* __restrict__ gw,
                                                   float* __restrict__ cvec) {
    const int d = blockIdx.x * 256 + threadIdx.x;
    float g = 0.f, a = 0.f;
#pragma unroll
    for (int j = 0; j < 16; ++j) {
        g += partG[(size_t)j * DDIM + d];
        a += partB[(size_t)j * DDIM + d];
    }
    gw[d]   = g;
    cvec[d] = a + b[d];
}

// ---------------------------------------------------------------------------
// Pass 1: per-row LN stats + normalize + convert to bf16.
// One wave per row; 4 rows per 256-thread block. xb[r][k] = (x-mean)*rstd.
// ---------------------------------------------------------------------------
__global__ __launch_bounds__(256) void ln_convert(const float* __restrict__ x,
                                                  bf16* __restrict__ xb) {
    const int wave = threadIdx.x >> 6;
    const int lane = threadIdx.x & 63;
    const int row  = blockIdx.x * 4 + wave;
    const float4* xr = (const float4*)(x + (size_t)row * KDIM);

    float4 v[4];
    float s1 = 0.f, s2 = 0.f;
#pragma unroll
    for (int j = 0; j < 4; ++j) {
        v[j] = xr[lane + j * 64];
        s1 += v[j].x + v[j].y + v[j].z + v[j].w;
        s2 += v[j].x * v[j].x + v[j].y * v[j].y + v[j].z * v[j].z + v[j].w * v[j].w;
    }
#pragma unroll
    for (int ofs = 1; ofs < 64; ofs <<= 1) {
        s1 += __shfl_xor(s1, ofs, 64);
        s2 += __shfl_xor(s2, ofs, 64);
    }
    const float mean = s1 * (1.0f / KDIM);
    const float var  = s2 * (1.0f / KDIM) - mean * mean;
    const float rstd = rsqrtf(var + 1e-5f);

    bf16x4* xo = (bf16x4*)(xb + (size_t)row * KDIM);
#pragma unroll
    for (int j = 0; j < 4; ++j) {
        bf16x4 o;
        o[0] = (bf16)((v[j].x - mean) * rstd);
        o[1] = (bf16)((v[j].y - mean) * rstd);
        o[2] = (bf16)((v[j].z - mean) * rstd);
        o[3] = (bf16)((v[j].w - mean) * rstd);
        xo[lane + j * 64] = o;
    }
}

// ---------------------------------------------------------------------------
// Pass 2: 256x256-tile bf16 GEMM, 8 waves (2Mx4N), BK=64, K-split halves,
// 4-phase interleaved schedule with counted vmcnt(4) (T2+T3+T4+T5) and
// XCD-bijective block swizzle (T1).
//
// LDS: As/Bs[buf][khalf][256 rows x 32 k], 16 KiB per region, 128 KiB total.
// Swizzle: within each 64B row, 16B chunk q holds global chunk q^(r&3);
// global_load_lds dest stays linear, source carries the inverse permutation.
// ds_read_b128 of a frag then lands 2 lanes/4-bank-span -> conflict-free.
//
// Schedule per K-tile t (buf c=t&1, stages go to buf c^1 = tile t+1):
//   P0: read A m0-3/ks0 + B n0-3/ks0   | stage A-K0(t+1) | bar | MFMA | bar
//   P1: read A m4-7/ks0                | stage B-K0(t+1) | vmcnt(4) | bar | MFMA | bar
//   P2: read A m0-3/ks1 + B n0-3/ks1   | stage A-K1(t+1) | bar | MFMA | bar
//   P3: read A m4-7/ks1                | stage B-K1(t+1) | vmcnt(4) | bar | MFMA | bar
// vmcnt(4) at P1 guarantees this tile's K1 halves (issued 4 loads back);
// vmcnt(4) at P3 guarantees next tile's K0 halves. Never drains to 0 except
// the peeled last tile. Write-safety: stages target the opposite buffer,
// whose last readers finished >=1 barrier earlier.
// ---------------------------------------------------------------------------
__device__ __forceinline__ void stage_half(const bf16* __restrict__ g0,
                                           bf16* lregion, int kt, int h, int tid) {
#pragma unroll
    for (int j = 0; j < 2; ++j) {
        const int ci = j * 512 + tid;       // 16B chunk index, 1024 chunks = 16KB
        const int r  = ci >> 2;             // row 0..255
        const int qs = (ci & 3) ^ (r & 3);  // inverse (involution) of read swizzle
        const bf16* gp = g0 + (size_t)r * KDIM + kt * 64 + h * 32 + qs * 8;
        char* lp = (char*)lregion + ci * 16;
        __builtin_amdgcn_global_load_lds((gas_ptr)(const void*)gp,
                                         (las_ptr)(void*)lp, 16, 0, 0);
    }
}

__device__ __forceinline__ bf16x8 ld_frag(const bf16* region, int r, int g) {
    return *(const bf16x8*)(region + r * 32 + ((g ^ (r & 3)) * 8));
}

#define MFMA_QUAD(MOFF)                                                         \
    __builtin_amdgcn_s_setprio(1);                                              \
    _Pragma("unroll")                                                           \
    for (int m_ = 0; m_ < 4; ++m_) {                                            \
        _Pragma("unroll")                                                       \
        for (int n_ = 0; n_ < 4; ++n_)                                          \
            acc[(MOFF) + m_][n_] = __builtin_amdgcn_mfma_f32_16x16x32_bf16(     \
                af[m_], bfr[n_], acc[(MOFF) + m_][n_], 0, 0, 0);                \
    }                                                                           \
    __builtin_amdgcn_s_setprio(0);

__global__ __launch_bounds__(512, 2) void gemm256(const bf16* __restrict__ xb,
                                                  const bf16* __restrict__ Gt,
                                                  const float* __restrict__ cvec,
                                                  float* __restrict__ out) {
    __shared__ __align__(16) bf16 As[2][2][8192];   // [buf][khalf][256*32]
    __shared__ __align__(16) bf16 Bs[2][2][8192];

    const int tid  = threadIdx.x;
    const int bid  = blockIdx.x;
    // XCD-bijective swizzle: 512 blocks, 64 contiguous wgids per XCD
    const int wg   = (bid & 7) * 64 + (bid >> 3);
    const int mT   = wg >> 2;          // 0..127
    const int dT   = wg & 3;           // 0..3 (4 dTiles of one mTile share an XCD/L2)
    const int row0 = mT * 256;
    const int col0 = dT * 256;

    const int wave = tid >> 6;
    const int lane = tid & 63;
    const int wm   = wave >> 2;        // 0..1  (128-row half of A)
    const int wn   = wave & 3;         // 0..3  (64-col slice of B)
    const int r16  = lane & 15;
    const int g    = lane >> 4;        // k-chunk 0..3 within K-half

    const bf16* aG = xb + (size_t)row0 * KDIM;
    const bf16* bG = Gt + (size_t)col0 * KDIM;

    f32x4 acc[8][4];
#pragma unroll
    for (int m = 0; m < 8; ++m)
#pragma unroll
        for (int n = 0; n < 4; ++n) acc[m][n] = (f32x4)0.0f;

    // Prologue: tile 0 -> buf 0. Order: A-K0, B-K0, A-K1, B-K1 (8 loads).
    stage_half(aG, &As[0][0][0], 0, 0, tid);
    stage_half(bG, &Bs[0][0][0], 0, 0, tid);
    stage_half(aG, &As[0][1][0], 0, 1, tid);
    stage_half(bG, &Bs[0][1][0], 0, 1, tid);
    asm volatile("s_waitcnt vmcnt(4)" ::: "memory");   // K0 halves landed
    __builtin_amdgcn_s_barrier();

    bf16x8 af[4], bfr[4];
    for (int t = 0; t < 16; ++t) {
        const int  c  = t & 1;
        const int  o  = c ^ 1;
        const bool st = (t < 15);
        const bf16* A0 = &As[c][0][0];
        const bf16* A1 = &As[c][1][0];
        const bf16* B0 = &Bs[c][0][0];
        const bf16* B1 = &Bs[c][1][0];
        const int am = wm * 128 + r16;
        const int bn = wn * 64 + r16;

        // ---- P0: A m0-3 ks0 + B n0-3 ks0; stage A-K0(t+1)
#pragma unroll
        for (int m = 0; m < 4; ++m) af[m] = ld_frag(A0, am + m * 16, g);
#pragma unroll
        for (int n = 0; n < 4; ++n) bfr[n] = ld_frag(B0, bn + n * 16, g);
        if (st) stage_half(aG, &As[o][0][0], t + 1, 0, tid);
        __builtin_amdgcn_s_barrier();
        MFMA_QUAD(0)
        __builtin_amdgcn_s_barrier();

        // ---- P1: A m4-7 ks0 (B ks0 held in regs); stage B-K0(t+1); counted wait
#pragma unroll
        for (int m = 0; m < 4; ++m) af[m] = ld_frag(A0, am + 64 + m * 16, g);
        if (st) {
            stage_half(bG, &Bs[o][0][0], t + 1, 0, tid);
            asm volatile("s_waitcnt vmcnt(4)" ::: "memory");  // this tile's K1 done
        } else {
            asm volatile("s_waitcnt vmcnt(0)" ::: "memory");  // peeled last tile
        }
        __builtin_amdgcn_s_barrier();
        MFMA_QUAD(4)
        __builtin_amdgcn_s_barrier();

        // ---- P2: A m0-3 ks1 + B n0-3 ks1; stage A-K1(t+1)
#pragma unroll
        for (int m = 0; m < 4; ++m) af[m] = ld_frag(A1, am + m * 16, g);
#pragma unroll
        for (int n = 0; n < 4; ++n) bfr[n] = ld_frag(B1, bn + n * 16, g);
        if (st) stage_half(aG, &As[o][1][0], t + 1, 1, tid);
        __builtin_amdgcn_s_barrier();
        MFMA_QUAD(0)
        __builtin_amdgcn_s_barrier();

        // ---- P3: A m4-7 ks1; stage B-K1(t+1); counted wait for next tile's K0
#pragma unroll
        for (int m = 0; m < 4; ++m) af[m] = ld_frag(A1, am + 64 + m * 16, g);
        if (st) {
            stage_half(bG, &Bs[o][1][0], t + 1, 1, tid);
            asm volatile("s_waitcnt vmcnt(4)" ::: "memory");  // next tile's K0 done
        }
        __builtin_amdgcn_s_barrier();
        MFMA_QUAD(4)
        __builtin_amdgcn_s_barrier();
    }

    // Epilogue: + cvec[d]
#pragma unroll
    for (int n = 0; n < 4; ++n) {
        const int colL = wn * 64 + n * 16 + r16;
        const float cv = cvec[col0 + colL];
#pragma unroll
        for (int m = 0; m < 8; ++m) {
#pragma unroll
            for (int rg = 0; rg < 4; ++rg) {
                const int rowL = wm * 128 + m * 16 + g * 4 + rg;
                out[(size_t)(row0 + rowL) * DDIM + col0 + colL] = acc[m][n][rg] + cv;
            }
        }
    }
}

// ---------------------------------------------------------------------------
// Fallback (small ws): round-1 fused kernel — LN stats inline, gw/mean epilogue.
// ---------------------------------------------------------------------------
#define BM 128
#define BN 128
#define FBK 32
#define APAD 40

__global__ __launch_bounds__(256) void fused_gemm(const float* __restrict__ x,
                                                  const bf16* __restrict__ Gt,
                                                  const float* __restrict__ gw,
                                                  const float* __restrict__ cvec,
                                                  float* __restrict__ out) {
    __shared__ __align__(16) bf16 As2[BM * APAD];
    __shared__ __align__(16) bf16 Bs2[BM * FBK];
    __shared__ float meanS[BM];
    __shared__ float rstdS[BM];

    const int t     = threadIdx.x;
    const int mTile = blockIdx.x;
    const int dTile = blockIdx.y;
    const int row0  = mTile * BM;
    const int col0  = dTile * BN;
    const int wave = t >> 6;
    const int lane = t & 63;
    const int wr   = wave >> 1;
    const int wc   = wave & 1;
    const int a_row = t >> 3;
    const int a_seg = t & 7;

    float s1[4] = {0.f, 0.f, 0.f, 0.f};
    float s2[4] = {0.f, 0.f, 0.f, 0.f};
    f32x4 acc[4][4];
#pragma unroll
    for (int i = 0; i < 4; ++i)
#pragma unroll
        for (int j = 0; j < 4; ++j) acc[i][j] = (f32x4)0.0f;

    for (int k0 = 0; k0 < KDIM; k0 += FBK) {
        __syncthreads();
#pragma unroll
        for (int j = 0; j < 2; ++j) {
            const int off  = j * 4096 + t * 16;
            const int brow = off >> 6;
            const int kseg = (off & 63) >> 1;
            const bf16* gp = Gt + (size_t)(col0 + brow) * KDIM + k0 + kseg;
            char* lp = (char*)Bs2 + off;
            __builtin_amdgcn_global_load_lds((gas_ptr)(const void*)gp,
                                             (las_ptr)(void*)lp, 16, 0, 0);
        }
#pragma unroll
        for (int r = 0; r < 4; ++r) {
            const int row = r * 32 + a_row;
            const float4 v = *(const float4*)&x[(size_t)(row0 + row) * KDIM + k0 + a_seg * 4];
            s1[r] += v.x + v.y + v.z + v.w;
            s2[r] += v.x * v.x + v.y * v.y + v.z * v.z + v.w * v.w;
            bf16x4 pk;
            pk[0] = (bf16)v.x; pk[1] = (bf16)v.y; pk[2] = (bf16)v.z; pk[3] = (bf16)v.w;
            *(bf16x4*)&As2[row * APAD + a_seg * 4] = pk;
        }
        __syncthreads();

        bf16x8 af[4], bfr[4];
        const int arow = wr * 64 + (lane & 15);
        const int brow = wc * 64 + (lane & 15);
        const int koff = (lane >> 4) * 8;
#pragma unroll
        for (int i = 0; i < 4; ++i)
            af[i] = *(const bf16x8*)&As2[(arow + i * 16) * APAD + koff];
#pragma unroll
        for (int j = 0; j < 4; ++j)
            bfr[j] = *(const bf16x8*)&Bs2[(brow + j * 16) * FBK + koff];
#pragma unroll
        for (int i = 0; i < 4; ++i)
#pragma unroll
            for (int j = 0; j < 4; ++j)
                acc[i][j] = __builtin_amdgcn_mfma_f32_16x16x32_bf16(af[i], bfr[j], acc[i][j], 0, 0, 0);
    }

#pragma unroll
    for (int r = 0; r < 4; ++r) {
        float a = s1[r], b = s2[r];
#pragma unroll
        for (int ofs = 1; ofs < 8; ofs <<= 1) {
            a += __shfl_xor(a, ofs, 64);
            b += __shfl_xor(b, ofs, 64);
        }
        if (a_seg == 0) {
            const int row = r * 32 + a_row;
            const float mean = a * (1.0f / KDIM);
            const float var  = b * (1.0f / KDIM) - mean * mean;
            meanS[row] = mean;
            rstdS[row] = rsqrtf(var + 1e-5f);
        }
    }
    __syncthreads();

    const int lr = (lane >> 4) * 4;
    const int lc = lane & 15;
#pragma unroll
    for (int j = 0; j < 4; ++j) {
        const int col = col0 + wc * 64 + j * 16 + lc;
        const float gwv = gw[col];
        const float cv  = cvec[col];
#pragma unroll
        for (int i = 0; i < 4; ++i) {
#pragma unroll
            for (int rg = 0; rg < 4; ++rg) {
                const int rowL = wr * 64 + i * 16 + lr + rg;
                const float vv = rstdS[rowL] * (acc[i][j][rg] - meanS[rowL] * gwv) + cv;
                out[(size_t)(row0 + rowL) * DDIM + col] = vv;
            }
        }
    }
}

// ---------------------------------------------------------------------------
extern "C" void kernel_launch(void* const* d_in, const int* in_sizes, int n_in,
                              void* d_out, int out_size, void* d_ws, size_t ws_size,
                              hipStream_t stream) {
    const float* x     = (const float*)d_in[0];
    const float* w     = (const float*)d_in[1];
    const float* b     = (const float*)d_in[2];
    const float* gamma = (const float*)d_in[3];
    const float* beta  = (const float*)d_in[4];
    float* out = (float*)d_out;

    char* ws = (char*)d_ws;
    // Layout: xb (64MB) | Gt (2MB) | partG (64KB) | partB (64KB) | gw (4KB) | cvec (4KB)
    const size_t XB_B = (size_t)RROWS * KDIM * sizeof(bf16);   // 67,108,864
    bf16*  xb    = (bf16*)ws;
    bf16*  Gt    = (bf16*)(ws + XB_B);
    float* partG = (float*)(ws + XB_B + (2u << 20));
    float* partB = (float*)(ws + XB_B + (2u << 20) + (64u << 10));
    float* gw    = (float*)(ws + XB_B + (2u << 20) + (128u << 10));
    float* cvec  = (float*)(ws + XB_B + (2u << 20) + (132u << 10));

    const bool big_ws = ws_size >= XB_B + (3u << 20);

    if (big_ws) {
        prep_gt<<<dim3(16, 16), 256, 0, stream>>>(w, gamma, Gt);
        prep_part<<<dim3(4, 16), 256, 0, stream>>>(w, gamma, beta, partG, partB);
        prep_reduce<<<4, 256, 0, stream>>>(partG, partB, b, gw, cvec);
        ln_convert<<<RROWS / 4, 256, 0, stream>>>(x, xb);
        gemm256<<<dim3(512), 512, 0, stream>>>(xb, Gt, cvec, out);
    } else {
        // small scratch: round-1 fused path (needs ~2.2MB)
        bf16*  Gt2    = (bf16*)ws;
        float* partG2 = (float*)(ws + (2u << 20));
        float* partB2 = (float*)(ws + (2u << 20) + (64u << 10));
        float* gw2    = (float*)(ws + (2u << 20) + (128u << 10));
        float* cvec2  = (float*)(ws + (2u << 20) + (132u << 10));
        prep_gt<<<dim3(16, 16), 256, 0, stream>>>(w, gamma, Gt2);
        prep_part<<<dim3(4, 16), 256, 0, stream>>>(w, gamma, beta, partG2, partB2);
        prep_reduce<<<4, 256, 0, stream>>>(partG2, partB2, b, gw2, cvec2);
        fused_gemm<<<dim3(256, 8), 256, 0, stream>>>(x, Gt2, gw2, cvec2, out);
    }
}

// Round 2
// 315.793 us; speedup vs baseline: 1.0693x; 1.0678x over previous
//
#include <hip/hip_runtime.h>
#include <stdint.h>

// Problem constants (B=8, M=4096, N=K=1024, D=1024)
#define RROWS 32768   // B*M
#define KDIM  1024    // N
#define DDIM  1024

typedef __bf16 bf16;
typedef __bf16 bf16x4 __attribute__((ext_vector_type(4)));
typedef __bf16 bf16x8 __attribute__((ext_vector_type(8)));
typedef float  f32x4  __attribute__((ext_vector_type(4)));

typedef __attribute__((address_space(1))) const unsigned int* gas_ptr;
typedef __attribute__((address_space(3))) unsigned int* las_ptr;

// ---------------------------------------------------------------------------
// Prep 1: Gt[d][k] = gamma[k] * w[k][d]  (bf16, transposed). 64x64 LDS tiles.
// ---------------------------------------------------------------------------
__global__ __launch_bounds__(256) void prep_gt(const float* __restrict__ w,
                                               const float* __restrict__ gamma,
                                               bf16* __restrict__ Gt) {
    __shared__ float tile[64][65];
    const int k0 = blockIdx.x * 64;
    const int d0 = blockIdx.y * 64;
    const int t  = threadIdx.x;
    const int col4 = (t & 15) * 4;
    const int rowb = t >> 4;
#pragma unroll
    for (int r = 0; r < 4; ++r) {
        const int k = rowb + r * 16;
        const float4 v = *(const float4*)&w[(size_t)(k0 + k) * DDIM + d0 + col4];
        const float g = gamma[k0 + k];
        tile[k][col4 + 0] = v.x * g;
        tile[k][col4 + 1] = v.y * g;
        tile[k][col4 + 2] = v.z * g;
        tile[k][col4 + 3] = v.w * g;
    }
    __syncthreads();
#pragma unroll
    for (int r = 0; r < 2; ++r) {
        const int d  = (t >> 3) + r * 32;
        const int ks = (t & 7) * 8;
        bf16x8 o;
#pragma unroll
        for (int j = 0; j < 8; ++j) o[j] = (bf16)tile[ks + j][d];
        *(bf16x8*)&Gt[(size_t)(d0 + d) * KDIM + k0 + ks] = o;
    }
}

// ---------------------------------------------------------------------------
// Prep 2a/2b: gw[d] = sum_k gamma*w (fallback path only), cvec[d] = sum_k beta*w + b
// ---------------------------------------------------------------------------
__global__ __launch_bounds__(256) void prep_part(const float* __restrict__ w,
                                                 const float* __restrict__ gamma,
                                                 const float* __restrict__ beta,
                                                 float* __restrict__ partG,
                                                 float* __restrict__ partB) {
    const int d  = blockIdx.x * 256 + threadIdx.x;
    const int kc = blockIdx.y;
    float ag = 0.f, ab = 0.f;
    for (int k = kc * 64; k < kc * 64 + 64; ++k) {
        const float wv = w[(size_t)k * DDIM + d];
        ag += gamma[k] * wv;
        ab += beta[k] * wv;
    }
    partG[(size_t)kc * DDIM + d] = ag;
    partB[(size_t)kc * DDIM + d] = ab;
}

__global__ __launch_bounds__(256) void prep_reduce(const float* __restrict__ partG,
                                                   const float* __restrict__ partB,
                                                   const float* __restrict__ b,
                                                   float* __restrict__ gw,
                                                   float* __restrict__ cvec) {
    const int d = blockIdx.x * 256 + threadIdx.x;
    float g = 0.f, a = 0.f;
#pragma unroll
    for (int j = 0; j < 16; ++j) {
        g += partG[(size_t)j * DDIM + d];
        a += partB[(size_t)j * DDIM + d];
    }
    gw[d]   = g;
    cvec[d] = a + b[d];
}

// ---------------------------------------------------------------------------
// Pass 1: per-row LN stats + normalize + convert to bf16.
// ---------------------------------------------------------------------------
__global__ __launch_bounds__(256) void ln_convert(const float* __restrict__ x,
                                                  bf16* __restrict__ xb) {
    const int wave = threadIdx.x >> 6;
    const int lane = threadIdx.x & 63;
    const int row  = blockIdx.x * 4 + wave;
    const float4* xr = (const float4*)(x + (size_t)row * KDIM);

    float4 v[4];
    float s1 = 0.f, s2 = 0.f;
#pragma unroll
    for (int j = 0; j < 4; ++j) {
        v[j] = xr[lane + j * 64];
        s1 += v[j].x + v[j].y + v[j].z + v[j].w;
        s2 += v[j].x * v[j].x + v[j].y * v[j].y + v[j].z * v[j].z + v[j].w * v[j].w;
    }
#pragma unroll
    for (int ofs = 1; ofs < 64; ofs <<= 1) {
        s1 += __shfl_xor(s1, ofs, 64);
        s2 += __shfl_xor(s2, ofs, 64);
    }
    const float mean = s1 * (1.0f / KDIM);
    const float var  = s2 * (1.0f / KDIM) - mean * mean;
    const float rstd = rsqrtf(var + 1e-5f);

    bf16x4* xo = (bf16x4*)(xb + (size_t)row * KDIM);
#pragma unroll
    for (int j = 0; j < 4; ++j) {
        bf16x4 o;
        o[0] = (bf16)((v[j].x - mean) * rstd);
        o[1] = (bf16)((v[j].y - mean) * rstd);
        o[2] = (bf16)((v[j].z - mean) * rstd);
        o[3] = (bf16)((v[j].w - mean) * rstd);
        xo[lane + j * 64] = o;
    }
}

// ---------------------------------------------------------------------------
// Pass 2: 256x256 tile, BK=64 (full 128B LDS rows), 8 waves.
// Conflict-free chunk XOR: 16B chunk q of row r stored at slot q^(r&7)
// (span = slot; 16 consecutive rows cover all 8 spans 2x = free; measured 0
// conflicts with this pattern in gemm_bt). Staging granularity = row-halves
// (contiguous 16KB regions, linear global_load_lds dest).
//
// Interleaved frag assignment: wave wm owns A rows m*32+wm*16+r16 (m0-3 in
// A-lo, m4-7 in A-hi); wave wn owns cols n*64+wn*16+r16 (n0-1 B-lo, n2-3
// B-hi). Quadrant phases per K-tile (16 MFMA each, K=64):
//   p0 Q(m0-3,n0-1): read A-lo frags(8) + B-lo(4); stage A-lo(t+1); vmcnt(4)
//   p1 Q(m0-3,n2-3): read B-hi(4);                 stage B-lo(t+1); vmcnt(4)
//   p2 Q(m4-7,n2-3): read A-hi frags(8);           stage B-hi(t+1)
//   p3 Q(m4-7,n0-1): reuse (0 reads);              stage A-hi(t+1); vmcnt(4)
// Invariant entering each tile: [B-hi(t), A-hi(t)] (4 loads) in flight.
// Waits never drain below 4 except the peeled last tile.
// ---------------------------------------------------------------------------
__device__ __forceinline__ void stage_half(const bf16* __restrict__ g0,
                                           bf16* lhalf, int kt, int rowOff, int tid) {
#pragma unroll
    for (int j = 0; j < 2; ++j) {
        const int ci = j * 512 + tid;        // 16B chunk index 0..1023 (16KB)
        const int rl = ci >> 3;              // row within half 0..127
        const int q  = (ci & 7) ^ (rl & 7);  // global k-chunk for this slot
        const bf16* gp = g0 + (size_t)(rowOff + rl) * KDIM + kt * 64 + q * 8;
        char* lp = (char*)lhalf + ci * 16;
        __builtin_amdgcn_global_load_lds((gas_ptr)(const void*)gp,
                                         (las_ptr)(void*)lp, 16, 0, 0);
    }
}

__device__ __forceinline__ bf16x8 ld_frag(const bf16* base, int row, int qk) {
    return *(const bf16x8*)(base + row * 64 + (qk ^ (row & 7)) * 8);
}

#define MFMA_Q(MO, NO, AFR, BFR)                                               \
    __builtin_amdgcn_s_setprio(1);                                             \
    _Pragma("unroll")                                                          \
    for (int kk_ = 0; kk_ < 2; ++kk_) {                                        \
        _Pragma("unroll")                                                      \
        for (int mm_ = 0; mm_ < 4; ++mm_) {                                    \
            _Pragma("unroll")                                                  \
            for (int nn_ = 0; nn_ < 2; ++nn_)                                  \
                acc[(MO) + mm_][(NO) + nn_] =                                  \
                    __builtin_amdgcn_mfma_f32_16x16x32_bf16(                   \
                        AFR[mm_][kk_], BFR[nn_][kk_],                          \
                        acc[(MO) + mm_][(NO) + nn_], 0, 0, 0);                 \
        }                                                                      \
    }                                                                          \
    __builtin_amdgcn_s_setprio(0);

__global__ __launch_bounds__(512, 2) void gemm256(const bf16* __restrict__ xb,
                                                  const bf16* __restrict__ Gt,
                                                  const float* __restrict__ cvec,
                                                  float* __restrict__ out) {
    __shared__ __align__(16) bf16 As[2][256 * 64];   // 32KB per buf
    __shared__ __align__(16) bf16 Bs[2][256 * 64];   // total 128KB

    const int tid  = threadIdx.x;
    const int bid  = blockIdx.x;
    // XCD-bijective swizzle (512 % 8 == 0): 64 contiguous wgids per XCD.
    const int wg   = (bid & 7) * 64 + (bid >> 3);
    const int mT   = wg >> 2;          // 0..127
    const int dT   = wg & 3;           // 4 dTiles of one mTile share an XCD/L2
    const int row0 = mT * 256;
    const int col0 = dT * 256;

    const int wave = tid >> 6;
    const int lane = tid & 63;
    const int wm   = wave >> 2;        // 0..1
    const int wn   = wave & 3;         // 0..3
    const int r16  = lane & 15;
    const int g    = lane >> 4;        // k-chunk 0..3 within a K=32 half

    const bf16* aG = xb + (size_t)row0 * KDIM;
    const bf16* bG = Gt + (size_t)col0 * KDIM;

    f32x4 acc[8][4];
#pragma unroll
    for (int m = 0; m < 8; ++m)
#pragma unroll
        for (int n = 0; n < 4; ++n) acc[m][n] = (f32x4)0.0f;

    // Prologue: tile 0 -> buf 0, order A-lo, B-lo, B-hi, A-hi (8 loads).
    stage_half(aG, &As[0][0],        0, 0,   tid);
    stage_half(bG, &Bs[0][0],        0, 0,   tid);
    stage_half(bG, &Bs[0][128 * 64], 0, 128, tid);
    stage_half(aG, &As[0][128 * 64], 0, 128, tid);
    asm volatile("s_waitcnt vmcnt(4)" ::: "memory");   // A-lo + B-lo landed
    __builtin_amdgcn_s_barrier();

    bf16x8 af[4][2], bl[2][2], bh[2][2];

#pragma unroll 1
    for (int t = 0; t < 15; ++t) {
        const int c = t & 1;
        const int o = c ^ 1;
        const bf16* Ac = &As[c][0];
        const bf16* Bc = &Bs[c][0];

        // ---- p0: Q(m0-3, n0-1)
#pragma unroll
        for (int m = 0; m < 4; ++m) {
            const int r = m * 32 + wm * 16 + r16;
#pragma unroll
            for (int kk = 0; kk < 2; ++kk) af[m][kk] = ld_frag(Ac, r, kk * 4 + g);
        }
#pragma unroll
        for (int n = 0; n < 2; ++n) {
            const int r = n * 64 + wn * 16 + r16;
#pragma unroll
            for (int kk = 0; kk < 2; ++kk) bl[n][kk] = ld_frag(Bc, r, kk * 4 + g);
        }
        stage_half(aG, &As[o][0], t + 1, 0, tid);
        asm volatile("s_waitcnt vmcnt(4)" ::: "memory");  // B-hi(t) done
        __builtin_amdgcn_s_barrier();
        MFMA_Q(0, 0, af, bl)
        __builtin_amdgcn_s_barrier();

        // ---- p1: Q(m0-3, n2-3)
#pragma unroll
        for (int n = 0; n < 2; ++n) {
            const int r = (n + 2) * 64 + wn * 16 + r16;
#pragma unroll
            for (int kk = 0; kk < 2; ++kk) bh[n][kk] = ld_frag(Bc, r, kk * 4 + g);
        }
        stage_half(bG, &Bs[o][0], t + 1, 0, tid);
        asm volatile("s_waitcnt vmcnt(4)" ::: "memory");  // A-hi(t) done
        __builtin_amdgcn_s_barrier();
        MFMA_Q(0, 2, af, bh)
        __builtin_amdgcn_s_barrier();

        // ---- p2: Q(m4-7, n2-3)
#pragma unroll
        for (int m = 0; m < 4; ++m) {
            const int r = (m + 4) * 32 + wm * 16 + r16;
#pragma unroll
            for (int kk = 0; kk < 2; ++kk) af[m][kk] = ld_frag(Ac, r, kk * 4 + g);
        }
        stage_half(bG, &Bs[o][128 * 64], t + 1, 128, tid);
        __builtin_amdgcn_s_barrier();
        MFMA_Q(4, 2, af, bh)
        __builtin_amdgcn_s_barrier();

        // ---- p3: Q(m4-7, n0-1) — all frags resident
        stage_half(aG, &As[o][128 * 64], t + 1, 128, tid);
        asm volatile("s_waitcnt vmcnt(4)" ::: "memory");  // A-lo+B-lo(t+1) done
        __builtin_amdgcn_s_barrier();
        MFMA_Q(4, 0, af, bl)
        __builtin_amdgcn_s_barrier();
    }

    // ---- Peeled tile 15 (buf 1), no staging.
    {
        const bf16* Ac = &As[1][0];
        const bf16* Bc = &Bs[1][0];
#pragma unroll
        for (int m = 0; m < 4; ++m) {
            const int r = m * 32 + wm * 16 + r16;
#pragma unroll
            for (int kk = 0; kk < 2; ++kk) af[m][kk] = ld_frag(Ac, r, kk * 4 + g);
        }
#pragma unroll
        for (int n = 0; n < 2; ++n) {
            const int r = n * 64 + wn * 16 + r16;
#pragma unroll
            for (int kk = 0; kk < 2; ++kk) bl[n][kk] = ld_frag(Bc, r, kk * 4 + g);
        }
        asm volatile("s_waitcnt vmcnt(2)" ::: "memory");  // B-hi(15) done
        __builtin_amdgcn_s_barrier();
        MFMA_Q(0, 0, af, bl)
        __builtin_amdgcn_s_barrier();

#pragma unroll
        for (int n = 0; n < 2; ++n) {
            const int r = (n + 2) * 64 + wn * 16 + r16;
#pragma unroll
            for (int kk = 0; kk < 2; ++kk) bh[n][kk] = ld_frag(Bc, r, kk * 4 + g);
        }
        asm volatile("s_waitcnt vmcnt(0)" ::: "memory");  // A-hi(15) done
        __builtin_amdgcn_s_barrier();
        MFMA_Q(0, 2, af, bh)
        __builtin_amdgcn_s_barrier();

#pragma unroll
        for (int m = 0; m < 4; ++m) {
            const int r = (m + 4) * 32 + wm * 16 + r16;
#pragma unroll
            for (int kk = 0; kk < 2; ++kk) af[m][kk] = ld_frag(Ac, r, kk * 4 + g);
        }
        __builtin_amdgcn_s_barrier();
        MFMA_Q(4, 2, af, bh)
        MFMA_Q(4, 0, af, bl)
    }

    // Epilogue: + cvec[d]
#pragma unroll
    for (int n = 0; n < 4; ++n) {
        const int colL = n * 64 + wn * 16 + r16;
        const float cv = cvec[col0 + colL];
#pragma unroll
        for (int m = 0; m < 8; ++m) {
            const int rbase = m * 32 + wm * 16 + g * 4;
#pragma unroll
            for (int rg = 0; rg < 4; ++rg) {
                out[(size_t)(row0 + rbase + rg) * DDIM + col0 + colL] = acc[m][n][rg] + cv;
            }
        }
    }
}

// ---------------------------------------------------------------------------
// Fallback (small ws): round-1 fused kernel — LN stats inline, gw/mean epilogue.
// ---------------------------------------------------------------------------
#define BM 128
#define BN 128
#define FBK 32
#define APAD 40

__global__ __launch_bounds__(256) void fused_gemm(const float* __restrict__ x,
                                                  const bf16* __restrict__ Gt,
                                                  const float* __restrict__ gw,
                                                  const float* __restrict__ cvec,
                                                  float* __restrict__ out) {
    __shared__ __align__(16) bf16 As2[BM * APAD];
    __shared__ __align__(16) bf16 Bs2[BM * FBK];
    __shared__ float meanS[BM];
    __shared__ float rstdS[BM];

    const int t     = threadIdx.x;
    const int mTile = blockIdx.x;
    const int dTile = blockIdx.y;
    const int row0  = mTile * BM;
    const int col0  = dTile * BN;
    const int wave = t >> 6;
    const int lane = t & 63;
    const int wr   = wave >> 1;
    const int wc   = wave & 1;
    const int a_row = t >> 3;
    const int a_seg = t & 7;

    float s1[4] = {0.f, 0.f, 0.f, 0.f};
    float s2[4] = {0.f, 0.f, 0.f, 0.f};
    f32x4 acc[4][4];
#pragma unroll
    for (int i = 0; i < 4; ++i)
#pragma unroll
        for (int j = 0; j < 4; ++j) acc[i][j] = (f32x4)0.0f;

    for (int k0 = 0; k0 < KDIM; k0 += FBK) {
        __syncthreads();
#pragma unroll
        for (int j = 0; j < 2; ++j) {
            const int off  = j * 4096 + t * 16;
            const int brow = off >> 6;
            const int kseg = (off & 63) >> 1;
            const bf16* gp = Gt + (size_t)(col0 + brow) * KDIM + k0 + kseg;
            char* lp = (char*)Bs2 + off;
            __builtin_amdgcn_global_load_lds((gas_ptr)(const void*)gp,
                                             (las_ptr)(void*)lp, 16, 0, 0);
        }
#pragma unroll
        for (int r = 0; r < 4; ++r) {
            const int row = r * 32 + a_row;
            const float4 v = *(const float4*)&x[(size_t)(row0 + row) * KDIM + k0 + a_seg * 4];
            s1[r] += v.x + v.y + v.z + v.w;
            s2[r] += v.x * v.x + v.y * v.y + v.z * v.z + v.w * v.w;
            bf16x4 pk;
            pk[0] = (bf16)v.x; pk[1] = (bf16)v.y; pk[2] = (bf16)v.z; pk[3] = (bf16)v.w;
            *(bf16x4*)&As2[row * APAD + a_seg * 4] = pk;
        }
        __syncthreads();

        bf16x8 af[4], bfr[4];
        const int arow = wr * 64 + (lane & 15);
        const int brow = wc * 64 + (lane & 15);
        const int koff = (lane >> 4) * 8;
#pragma unroll
        for (int i = 0; i < 4; ++i)
            af[i] = *(const bf16x8*)&As2[(arow + i * 16) * APAD + koff];
#pragma unroll
        for (int j = 0; j < 4; ++j)
            bfr[j] = *(const bf16x8*)&Bs2[(brow + j * 16) * FBK + koff];
#pragma unroll
        for (int i = 0; i < 4; ++i)
#pragma unroll
            for (int j = 0; j < 4; ++j)
                acc[i][j] = __builtin_amdgcn_mfma_f32_16x16x32_bf16(af[i], bfr[j], acc[i][j], 0, 0, 0);
    }

#pragma unroll
    for (int r = 0; r < 4; ++r) {
        float a = s1[r], b = s2[r];
#pragma unroll
        for (int ofs = 1; ofs < 8; ofs <<= 1) {
            a += __shfl_xor(a, ofs, 64);
            b += __shfl_xor(b, ofs, 64);
        }
        if (a_seg == 0) {
            const int row = r * 32 + a_row;
            const float mean = a * (1.0f / KDIM);
            const float var  = b * (1.0f / KDIM) - mean * mean;
            meanS[row] = mean;
            rstdS[row] = rsqrtf(var + 1e-5f);
        }
    }
    __syncthreads();

    const int lr = (lane >> 4) * 4;
    const int lc = lane & 15;
#pragma unroll
    for (int j = 0; j < 4; ++j) {
        const int col = col0 + wc * 64 + j * 16 + lc;
        const float gwv = gw[col];
        const float cv  = cvec[col];
#pragma unroll
        for (int i = 0; i < 4; ++i) {
#pragma unroll
            for (int rg = 0; rg < 4; ++rg) {
                const int rowL = wr * 64 + i * 16 + lr + rg;
                const float vv = rstdS[rowL] * (acc[i][j][rg] - meanS[rowL] * gwv) + cv;
                out[(size_t)(row0 + rowL) * DDIM + col] = vv;
            }
        }
    }
}

// ---------------------------------------------------------------------------
extern "C" void kernel_launch(void* const* d_in, const int* in_sizes, int n_in,
                              void* d_out, int out_size, void* d_ws, size_t ws_size,
                              hipStream_t stream) {
    const float* x     = (const float*)d_in[0];
    const float* w     = (const float*)d_in[1];
    const float* b     = (const float*)d_in[2];
    const float* gamma = (const float*)d_in[3];
    const float* beta  = (const float*)d_in[4];
    float* out = (float*)d_out;

    char* ws = (char*)d_ws;
    // Layout: xb (64MB) | Gt (2MB) | partG (64KB) | partB (64KB) | gw (4KB) | cvec (4KB)
    const size_t XB_B = (size_t)RROWS * KDIM * sizeof(bf16);   // 67,108,864
    bf16*  xb    = (bf16*)ws;
    bf16*  Gt    = (bf16*)(ws + XB_B);
    float* partG = (float*)(ws + XB_B + (2u << 20));
    float* partB = (float*)(ws + XB_B + (2u << 20) + (64u << 10));
    float* gw    = (float*)(ws + XB_B + (2u << 20) + (128u << 10));
    float* cvec  = (float*)(ws + XB_B + (2u << 20) + (132u << 10));

    const bool big_ws = ws_size >= XB_B + (3u << 20);

    if (big_ws) {
        prep_gt<<<dim3(16, 16), 256, 0, stream>>>(w, gamma, Gt);
        prep_part<<<dim3(4, 16), 256, 0, stream>>>(w, gamma, beta, partG, partB);
        prep_reduce<<<4, 256, 0, stream>>>(partG, partB, b, gw, cvec);
        ln_convert<<<RROWS / 4, 256, 0, stream>>>(x, xb);
        gemm256<<<dim3(512), 512, 0, stream>>>(xb, Gt, cvec, out);
    } else {
        // small scratch: round-1 fused path (needs ~2.2MB)
        bf16*  Gt2    = (bf16*)ws;
        float* partG2 = (float*)(ws + (2u << 20));
        float* partB2 = (float*)(ws + (2u << 20) + (64u << 10));
        float* gw2    = (float*)(ws + (2u << 20) + (128u << 10));
        float* cvec2  = (float*)(ws + (2u << 20) + (132u << 10));
        prep_gt<<<dim3(16, 16), 256, 0, stream>>>(w, gamma, Gt2);
        prep_part<<<dim3(4, 16), 256, 0, stream>>>(w, gamma, beta, partG2, partB2);
        prep_reduce<<<4, 256, 0, stream>>>(partG2, partB2, b, gw2, cvec2);
        fused_gemm<<<dim3(256, 8), 256, 0, stream>>>(x, Gt2, gw2, cvec2, out);
    }
}